// Round 6
// baseline (214.674 us; speedup 1.0000x reference)
//
#include <hip/hip_runtime.h>
#include <hip/hip_bf16.h>
#include <stdint.h>

typedef __attribute__((ext_vector_type(8))) short s16x8;          // 8 bf16 (4 VGPRs)
typedef __attribute__((ext_vector_type(8))) unsigned short u16x8;
typedef __attribute__((ext_vector_type(4))) float f32x4;

#define D_FEAT 128
#define H2 128
#define BLOCK_THREADS 512
#define MW 64                        // edges per wave (M-tile)
#define NW 64                        // cols per wave (N-split across wave pairs)
#define EPB 256                      // distinct edges per block (4 M-groups x 64)

__device__ __forceinline__ unsigned short f2bf(float f) {
  uint32_t u = __float_as_uint(f);
  return (unsigned short)((u + 0x7fffu + ((u >> 16) & 1u)) >> 16);  // RNE
}

// ---------------- pre-conversion kernels ----------------
__global__ void k_cvt_x(const float* __restrict__ x, unsigned short* __restrict__ xb, int n8) {
  int i = blockIdx.x * blockDim.x + threadIdx.x;
  if (i >= n8) return;
  const f32x4* p = (const f32x4*)x + (size_t)i * 2;
  f32x4 a = p[0], b = p[1];
  u16x8 o;
  o[0] = f2bf(a[0]); o[1] = f2bf(a[1]); o[2] = f2bf(a[2]); o[3] = f2bf(a[3]);
  o[4] = f2bf(b[0]); o[5] = f2bf(b[1]); o[6] = f2bf(b[2]); o[7] = f2bf(b[3]);
  ((u16x8*)xb)[i] = o;
}

// W1 [256][128] fp32 row-major -> swizzled bf16 W1^T tile (64KB) in ws.
// Element (n,k) stored at n*256 + ((chunk ^ (n&7))<<3) + (k&7), chunk = k>>3.
__global__ void k_cvt_w1(const float* __restrict__ W1, unsigned short* __restrict__ w1t) {
  int tid = blockIdx.x * blockDim.x + threadIdx.x;   // 0..4095
  int chunk = tid >> 7;                               // 0..31
  int n = tid & 127;
  u16x8 o;
#pragma unroll
  for (int j = 0; j < 8; ++j)
    o[j] = f2bf(W1[(chunk * 8 + j) * H2 + n]);
  *(u16x8*)(w1t + (n << 8) + ((chunk ^ (n & 7)) << 3)) = o;
}

// ---------------- main fused kernel ----------------
template <bool XBF>
__global__ __launch_bounds__(BLOCK_THREADS, 4)   // 4 waves/SIMD => 2 blocks/CU
void k_edge_mlp(const float* __restrict__ xf,
                const unsigned short* __restrict__ xb,
                const int* __restrict__ eli,      // int32: [2][E]
                const float* __restrict__ W1,
                const unsigned short* __restrict__ w1ws,
                const float* __restrict__ b1,
                const float* __restrict__ W2,
                const float* __restrict__ b2,
                float* __restrict__ out, int E, int nNodes)
{
  __shared__ alignas(16) unsigned short w1t[H2 * 256];   // 64KB, swizzled W1^T
  float* part = (float*)w1t;   // 1KB overlay, used ONLY after all w1t reads end

  const int t0    = threadIdx.x;
  const int lane  = t0 & 63;
  const int wid   = t0 >> 6;
  const int wid_m = wid >> 1;    // 0..3 : which 64-edge group
  const int wid_n = wid & 1;     // 0..1 : which 64-col half
  const int c     = lane & 15;   // A-row-in-frag / B-col-in-frag
  const int g     = lane >> 4;   // k-subgroup (8 consecutive k)
  const int ch7   = c & 7;

  // ---- stage W1^T (bf16, swizzled) into LDS ----
  if (XBF) {
#pragma unroll
    for (int i = 0; i < 8; ++i) {
      int idx = i * BLOCK_THREADS + t0;             // 4096 chunks of 16B
      ((u16x8*)w1t)[idx] = ((const u16x8*)w1ws)[idx];
    }
  } else {
    int cg = t0 >> 7;         // 0..3
    int n  = t0 & 127;
#pragma unroll
    for (int i = 0; i < 8; ++i) {
      int ch = cg + 4 * i;    // 0..31
      u16x8 o;
#pragma unroll
      for (int j = 0; j < 8; ++j)
        o[j] = f2bf(W1[(ch * 8 + j) * H2 + n]);
      *(u16x8*)(w1t + (n << 8) + ((ch ^ (n & 7)) << 3)) = o;
    }
  }

  // ---- per-lane edge node offsets (4 edges per lane: m=0..3) ----
  const int gbase = blockIdx.x * EPB + wid_m * MW;
  unsigned ro[4], co[4];
#pragma unroll
  for (int m = 0; m < 4; ++m) {
    int e = gbase + m * 16 + c;
    e = e < E ? e : E - 1;
    int nr = eli[e];
    int nc = eli[E + e];
    nr = nr < 0 ? 0 : (nr >= nNodes ? nNodes - 1 : nr);   // defensive clamp
    nc = nc < 0 ? 0 : (nc >= nNodes ? nNodes - 1 : nc);
    ro[m] = (unsigned)nr * D_FEAT + g * 8;
    co[m] = (unsigned)nc * D_FEAT + g * 8;
  }

  __syncthreads();

  // A-fragment gather: kk selects 32-wide K slice; kk<4 -> row node, else col node
  auto loadA = [&](int kk, s16x8* dst) {
#pragma unroll
    for (int m = 0; m < 4; ++m) {
      unsigned off = (kk < 4 ? ro[m] : co[m]) + (unsigned)((kk & 3) * 32);
      if (XBF) {
        dst[m] = *(const s16x8*)(xb + off);
      } else {
        const f32x4* q = (const f32x4*)(xf + off);
        f32x4 a = q[0], b = q[1];
        s16x8 v;
        v[0] = (short)f2bf(a[0]); v[1] = (short)f2bf(a[1]);
        v[2] = (short)f2bf(a[2]); v[3] = (short)f2bf(a[3]);
        v[4] = (short)f2bf(b[0]); v[5] = (short)f2bf(b[1]);
        v[6] = (short)f2bf(b[2]); v[7] = (short)f2bf(b[3]);
        dst[m] = v;
      }
    }
  };

  f32x4 acc[4][4];
#pragma unroll
  for (int m = 0; m < 4; ++m)
#pragma unroll
    for (int f = 0; f < 4; ++f) {
      f32x4 z = {0.f, 0.f, 0.f, 0.f};
      acc[m][f] = z;
    }

  // depth-2 software pipeline
  s16x8 abuf[2][4];
  loadA(0, abuf[0]);
  loadA(1, abuf[1]);

  const unsigned bbase = ((unsigned)(wid_n * NW + c)) << 8;   // column base (shorts)

#pragma unroll
  for (int kk = 0; kk < 8; ++kk) {
    __builtin_amdgcn_s_setprio(1);
#pragma unroll
    for (int f = 0; f < 4; ++f) {
      // n = wid_n*64 + f*16 + c ; n&7 == c&7 ; f adds f*4096 shorts (8192B imm)
      s16x8 bfrag = *(const s16x8*)(w1t + bbase + (((kk * 4 + g) ^ ch7) << 3) + f * 4096);
#pragma unroll
      for (int m = 0; m < 4; ++m)
        acc[m][f] = __builtin_amdgcn_mfma_f32_16x16x32_bf16(abuf[kk & 1][m], bfrag, acc[m][f], 0, 0, 0);
    }
    __builtin_amdgcn_s_setprio(0);
    if (kk < 6) loadA(kk + 2, abuf[kk & 1]);   // refill slot consumed this iteration
  }

  // ---- epilogue: partial relu(h+b1)@W2 over this wave's 64 cols ----
  float b1v[4], w2v[4];
#pragma unroll
  for (int f = 0; f < 4; ++f) {
    int n = wid_n * NW + f * 16 + c;
    b1v[f] = b1[n];
    w2v[f] = W2[n];
  }
  const float b2s = b2[0];

  float sr[4][4];   // [m][r], fully unrolled -> registers
#pragma unroll
  for (int m = 0; m < 4; ++m) {
#pragma unroll
    for (int r = 0; r < 4; ++r) {
      float s = 0.f;
#pragma unroll
      for (int f = 0; f < 4; ++f) {
        float h = acc[m][f][r] + b1v[f];
        h = h > 0.f ? h : 0.f;
        s += h * w2v[f];
      }
#pragma unroll
      for (int msk = 1; msk < 16; msk <<= 1)
        s += __shfl_xor(s, msk, 64);   // reduce over the 16 c-lanes
      sr[m][r] = s;
    }
  }

  __syncthreads();   // ALL waves done reading w1t -> safe to overlay part[]

  if (wid_n == 0 && c == 0) {
#pragma unroll
    for (int m = 0; m < 4; ++m) {
      f32x4 p = {sr[m][0], sr[m][1], sr[m][2], sr[m][3]};
      *(f32x4*)&part[wid_m * 64 + m * 16 + g * 4] = p;
    }
  }
  __syncthreads();

  if (wid_n == 1 && c == 0) {
#pragma unroll
    for (int m = 0; m < 4; ++m) {
      int idx = wid_m * 64 + m * 16 + g * 4;
      f32x4 p = *(const f32x4*)&part[idx];
      int eb = gbase + m * 16 + g * 4;
      if (eb < E) {
        f32x4 o = {sr[m][0] + p[0] + b2s, sr[m][1] + p[1] + b2s,
                   sr[m][2] + p[2] + b2s, sr[m][3] + p[3] + b2s};
        *(f32x4*)(out + eb) = o;
      }
    }
  }
}

extern "C" void kernel_launch(void* const* d_in, const int* in_sizes, int n_in,
                              void* d_out, int out_size, void* d_ws, size_t ws_size,
                              hipStream_t stream) {
  const float* x   = (const float*)d_in[0];
  const int*   eli = (const int*)d_in[1];     // int32 per harness contract
  const float* W1  = (const float*)d_in[2];
  const float* b1  = (const float*)d_in[3];
  const float* W2  = (const float*)d_in[4];
  const float* b2  = (const float*)d_in[5];
  float* out = (float*)d_out;

  const int E      = in_sizes[1] / 2;
  const int nNodes = in_sizes[0] / D_FEAT;

  const size_t xbytes = (size_t)nNodes * D_FEAT * 2;   // bf16 copy of x
  const size_t need   = xbytes + 65536;                // + swizzled W1^T
  const bool bfpath   = (ws_size >= need);

  const int grid = (E + EPB - 1) / EPB;

  if (bfpath) {
    unsigned short* xbw  = (unsigned short*)d_ws;
    unsigned short* w1tw = (unsigned short*)((char*)d_ws + xbytes);
    int n8 = nNodes * D_FEAT / 8;
    k_cvt_x<<<(n8 + 255) / 256, 256, 0, stream>>>(x, xbw, n8);
    k_cvt_w1<<<16, 256, 0, stream>>>(W1, w1tw);
    k_edge_mlp<true><<<grid, BLOCK_THREADS, 0, stream>>>(
        x, xbw, eli, W1, w1tw, b1, W2, b2, out, E, nNodes);
  } else {
    k_edge_mlp<false><<<grid, BLOCK_THREADS, 0, stream>>>(
        x, nullptr, eli, W1, nullptr, b1, W2, b2, out, E, nNodes);
  }
}

// Round 7
// 137.203 us; speedup vs baseline: 1.5646x; 1.5646x over previous
//
#include <hip/hip_runtime.h>
#include <hip/hip_bf16.h>
#include <stdint.h>

typedef __attribute__((ext_vector_type(8))) short s16x8;          // 8 bf16 (4 VGPRs)
typedef __attribute__((ext_vector_type(8))) unsigned short u16x8;
typedef __attribute__((ext_vector_type(4))) float f32x4;

#define D_FEAT 128
#define H2 128
#define BLOCK_THREADS 512
#define WAVES 8
#define MW 32                        // edges per wave (M-tile)
#define EPB (WAVES * MW)             // 256 edges per block

__device__ __forceinline__ unsigned short f2bf(float f) {
  uint32_t u = __float_as_uint(f);
  return (unsigned short)((u + 0x7fffu + ((u >> 16) & 1u)) >> 16);  // RNE
}

// ---------------- pre-conversion kernels ----------------
__global__ void k_cvt_x(const float* __restrict__ x, unsigned short* __restrict__ xb, int n8) {
  int i = blockIdx.x * blockDim.x + threadIdx.x;
  if (i >= n8) return;
  const f32x4* p = (const f32x4*)x + (size_t)i * 2;
  f32x4 a = p[0], b = p[1];
  u16x8 o;
  o[0] = f2bf(a[0]); o[1] = f2bf(a[1]); o[2] = f2bf(a[2]); o[3] = f2bf(a[3]);
  o[4] = f2bf(b[0]); o[5] = f2bf(b[1]); o[6] = f2bf(b[2]); o[7] = f2bf(b[3]);
  ((u16x8*)xb)[i] = o;
}

// W1 [256][128] fp32 -> bf16 "fragment-sequential" image (64KB) in ws.
// Chunk index = (kk*8 + f)*64 + lane, lane = (g<<4)|c. Chunk holds the 8
// B-frag elements j: W1[k = kk*32 + g*8 + j][n = f*16 + c].
// A wave reading (kk,f) touches chunks [ (kk*8+f)*64 .. +64 ) = 1KB contiguous
// at addr = base + lane*16  ->  zero bank conflicts, zero per-read VALU.
__global__ void k_cvt_w1(const float* __restrict__ W1, unsigned short* __restrict__ w1s) {
  int tid = blockIdx.x * blockDim.x + threadIdx.x;   // 0..4095
  int lane = tid & 63;
  int kkf  = tid >> 6;        // kk*8 + f
  int kk = kkf >> 3, f = kkf & 7;
  int c = lane & 15, g = lane >> 4;
  int n = f * 16 + c;
  u16x8 o;
#pragma unroll
  for (int j = 0; j < 8; ++j)
    o[j] = f2bf(W1[(kk * 32 + g * 8 + j) * H2 + n]);
  ((u16x8*)w1s)[tid] = o;
}

// ---------------- main fused kernel ----------------
template <bool XBF>
__global__ __launch_bounds__(BLOCK_THREADS, 4)   // 4 waves/SIMD => 2 blocks/CU
void k_edge_mlp(const float* __restrict__ xf,
                const unsigned short* __restrict__ xb,
                const int* __restrict__ eli,      // int32: [2][E]
                const float* __restrict__ W1,
                const unsigned short* __restrict__ w1ws,
                const float* __restrict__ b1,
                const float* __restrict__ W2,
                const float* __restrict__ b2,
                float* __restrict__ out, int E, int nNodes)
{
  __shared__ alignas(16) unsigned short w1t[H2 * 256];   // 64KB fragment-sequential
  const int t0   = threadIdx.x;
  const int lane = t0 & 63;
  const int wid  = t0 >> 6;
  const int c    = lane & 15;   // A-row-in-frag / B-col-in-frag
  const int g    = lane >> 4;   // k-subgroup (8 consecutive k)

  // ---- stage W1 image into LDS ----
  if (XBF) {
#pragma unroll
    for (int i = 0; i < 8; ++i) {
      int idx = i * BLOCK_THREADS + t0;             // 4096 chunks of 16B, linear
      ((u16x8*)w1t)[idx] = ((const u16x8*)w1ws)[idx];
    }
  } else {
#pragma unroll
    for (int i = 0; i < 8; ++i) {
      int chunk = i * BLOCK_THREADS + t0;           // 0..4095
      int cl  = chunk & 63;
      int kkf = chunk >> 6;
      int kk = kkf >> 3, f = kkf & 7;
      int cc = cl & 15, gg = cl >> 4;
      int n = f * 16 + cc;
      u16x8 o;
#pragma unroll
      for (int j = 0; j < 8; ++j)
        o[j] = f2bf(W1[(kk * 32 + gg * 8 + j) * H2 + n]);
      ((u16x8*)w1t)[chunk] = o;
    }
  }

  // ---- per-lane edge node offsets (2 edges per lane: m=0,1) ----
  const int gbase = blockIdx.x * EPB + wid * MW;
  unsigned ro[2], co[2];
#pragma unroll
  for (int m = 0; m < 2; ++m) {
    int e = gbase + m * 16 + c;
    e = e < E ? e : E - 1;
    int nr = eli[e];
    int nc = eli[E + e];
    nr = nr < 0 ? 0 : (nr >= nNodes ? nNodes - 1 : nr);   // defensive clamp
    nc = nc < 0 ? 0 : (nc >= nNodes ? nNodes - 1 : nc);
    ro[m] = (unsigned)nr * D_FEAT + g * 8;
    co[m] = (unsigned)nc * D_FEAT + g * 8;
  }

  __syncthreads();

  // A-fragment gather: kk selects 32-wide K slice; kk<4 -> row node, else col node
  auto loadA = [&](int kk, s16x8* dst) {
#pragma unroll
    for (int m = 0; m < 2; ++m) {
      unsigned off = (kk < 4 ? ro[m] : co[m]) + (unsigned)((kk & 3) * 32);
      if (XBF) {
        dst[m] = *(const s16x8*)(xb + off);
      } else {
        const f32x4* q = (const f32x4*)(xf + off);
        f32x4 a = q[0], b = q[1];
        s16x8 v;
        v[0] = (short)f2bf(a[0]); v[1] = (short)f2bf(a[1]);
        v[2] = (short)f2bf(a[2]); v[3] = (short)f2bf(a[3]);
        v[4] = (short)f2bf(b[0]); v[5] = (short)f2bf(b[1]);
        v[6] = (short)f2bf(b[2]); v[7] = (short)f2bf(b[3]);
        dst[m] = v;
      }
    }
  };

  f32x4 acc[2][8];
#pragma unroll
  for (int m = 0; m < 2; ++m)
#pragma unroll
    for (int f = 0; f < 8; ++f) {
      f32x4 z = {0.f, 0.f, 0.f, 0.f};
      acc[m][f] = z;
    }

  // depth-2 software pipeline — occupancy (4 waves/SIMD) hides the rest
  s16x8 abuf[2][2];
  loadA(0, abuf[0]);
  loadA(1, abuf[1]);

  // single shared LDS base; every read below is base + compile-time offset
  const unsigned short* bbase = w1t + (unsigned)lane * 8;   // lane*16B

#pragma unroll
  for (int kk = 0; kk < 8; ++kk) {
    __builtin_amdgcn_s_setprio(1);
#pragma unroll
    for (int f = 0; f < 8; ++f) {
      s16x8 bfrag = *(const s16x8*)(bbase + (kk * 8 + f) * 512);  // offset:(kk*8+f)*1024B
#pragma unroll
      for (int m = 0; m < 2; ++m)
        acc[m][f] = __builtin_amdgcn_mfma_f32_16x16x32_bf16(abuf[kk & 1][m], bfrag, acc[m][f], 0, 0, 0);
    }
    __builtin_amdgcn_s_setprio(0);
    if (kk < 6) loadA(kk + 2, abuf[kk & 1]);   // refill slot consumed this iteration
  }

  // ---- fused epilogue: relu(h + b1) @ W2 + b2, fp32 ----
  float b1v[8], w2v[8];
#pragma unroll
  for (int f = 0; f < 8; ++f) {
    b1v[f] = b1[f * 16 + c];
    w2v[f] = W2[f * 16 + c];
  }
  const float b2s = b2[0];

#pragma unroll
  for (int m = 0; m < 2; ++m) {
    float sr[4];
#pragma unroll
    for (int r = 0; r < 4; ++r) {
      float s = 0.f;
#pragma unroll
      for (int f = 0; f < 8; ++f) {
        float h = acc[m][f][r] + b1v[f];
        h = h > 0.f ? h : 0.f;
        s += h * w2v[f];
      }
#pragma unroll
      for (int msk = 1; msk < 16; msk <<= 1)
        s += __shfl_xor(s, msk, 64);   // reduce over the 16 c-lanes
      sr[r] = s;
    }
    int ebase = gbase + m * 16 + g * 4;
    if (c == 0 && ebase < E) {
      f32x4 o = {sr[0] + b2s, sr[1] + b2s, sr[2] + b2s, sr[3] + b2s};
      *(f32x4*)(out + ebase) = o;
    }
  }
}

extern "C" void kernel_launch(void* const* d_in, const int* in_sizes, int n_in,
                              void* d_out, int out_size, void* d_ws, size_t ws_size,
                              hipStream_t stream) {
  const float* x   = (const float*)d_in[0];
  const int*   eli = (const int*)d_in[1];     // int32 per harness contract
  const float* W1  = (const float*)d_in[2];
  const float* b1  = (const float*)d_in[3];
  const float* W2  = (const float*)d_in[4];
  const float* b2  = (const float*)d_in[5];
  float* out = (float*)d_out;

  const int E      = in_sizes[1] / 2;
  const int nNodes = in_sizes[0] / D_FEAT;

  const size_t xbytes = (size_t)nNodes * D_FEAT * 2;   // bf16 copy of x
  const size_t need   = xbytes + 65536;                // + W1 fragment image
  const bool bfpath   = (ws_size >= need);

  const int grid = (E + EPB - 1) / EPB;

  if (bfpath) {
    unsigned short* xbw  = (unsigned short*)d_ws;
    unsigned short* w1sw = (unsigned short*)((char*)d_ws + xbytes);
    int n8 = nNodes * D_FEAT / 8;
    k_cvt_x<<<(n8 + 255) / 256, 256, 0, stream>>>(x, xbw, n8);
    k_cvt_w1<<<16, 256, 0, stream>>>(W1, w1sw);
    k_edge_mlp<true><<<grid, BLOCK_THREADS, 0, stream>>>(
        x, xbw, eli, W1, w1sw, b1, W2, b2, out, E, nNodes);
  } else {
    k_edge_mlp<false><<<grid, BLOCK_THREADS, 0, stream>>>(
        x, nullptr, eli, W1, nullptr, b1, W2, b2, out, E, nNodes);
  }
}